// Round 3
// baseline (535.897 us; speedup 1.0000x reference)
//
#include <hip/hip_runtime.h>

#define BATCH 64
#define SEQ   4096
#define DECD  512
#define ENC   256
#define TS    256                // positions per block in main kernel (8 waves x 32 rows)
#define NCHUNK (SEQ / TS)        // 16 chunks per batch
#define OUT_ATTN (BATCH * ENC)   // offset of attn region in d_out

typedef short  short8  __attribute__((ext_vector_type(8)));
typedef float  floatx4 __attribute__((ext_vector_type(4)));

__device__ __forceinline__ short f2bf(float f) {
    union { float f; unsigned u; } v; v.f = f;
    unsigned u = v.u;
    u += 0x7FFFu + ((u >> 16) & 1u);
    return (short)(u >> 16);
}

__device__ __forceinline__ float fast_tanh(float x) {
    // tanh(x) = 1 - 2/(e^{2x}+1); v_rcp_f32 approx is plenty for bf16-level tol
    x = fminf(fmaxf(x, -9.0f), 9.0f);
    float e2 = __expf(2.0f * x);
    float r  = __builtin_amdgcn_rcpf(e2 + 1.0f);
    return fmaf(-2.0f, r, 1.0f);
}

// Kernel 1 (split-K x4): dpb4[(b*4+j)][e] = sum_{d in j-th 128-slice} dh[b,d]*Wd[d,e]
//                        (+ bd[e]+be[e] on j==0)
__global__ void dp_kernel(const float* __restrict__ dh,
                          const float* __restrict__ Wd,
                          const float* __restrict__ bd,
                          const float* __restrict__ be,
                          float* __restrict__ dpb4) {
    __shared__ float dhs[128];
    int blk = blockIdx.x, b = blk >> 2, j = blk & 3;
    int t = threadIdx.x;
    if (t < 128) dhs[t] = dh[b * DECD + j * 128 + t];
    __syncthreads();
    const float* wp = Wd + (size_t)(j * 128) * ENC + t;
    float a0 = 0.f, a1 = 0.f, a2 = 0.f, a3 = 0.f;
#pragma unroll 4
    for (int d = 0; d < 128; d += 4) {
        a0 = fmaf(dhs[d],     wp[(size_t)(d)     * ENC], a0);
        a1 = fmaf(dhs[d + 1], wp[(size_t)(d + 1) * ENC], a1);
        a2 = fmaf(dhs[d + 2], wp[(size_t)(d + 2) * ENC], a2);
        a3 = fmaf(dhs[d + 3], wp[(size_t)(d + 3) * ENC], a3);
    }
    float r = (a0 + a1) + (a2 + a3);
    if (j == 0) r += bd[t] + be[t];
    dpb4[(size_t)(b * 4 + j) * ENC + t] = r;
}

// Kernel 2: pack We (fp32 [K=256][N=256]) into bf16 MFMA B-fragment layout:
// WeF[((kt*16+nt)*64+lane)*8 + j] = bf16( We[kt*32 + (lane>>4)*8 + j][nt*16 + (lane&15)] )
__global__ void pack_kernel(const float* __restrict__ We, short* __restrict__ WeF) {
    int gid  = blockIdx.x * 256 + threadIdx.x;   // 0..8191
    int lane = gid & 63;
    int nt   = (gid >> 6) & 15;
    int kt   = gid >> 10;
    int quad = lane >> 4, l16 = lane & 15;
    int n = nt * 16 + l16;
    short8 v;
#pragma unroll
    for (int j = 0; j < 8; ++j) {
        int k = kt * 32 + quad * 8 + j;
        v[j] = f2bf(We[k * ENC + n]);
    }
    *(short8*)(WeF + gid * 8) = v;
}

// Kernel 3 (main): block = (batch b, chunk of 256 positions); wave = 32 rows (2 M-tiles).
// B fragments straight from L1/L2 (WeF hot, 128KB); NO barriers in the K-loop.
__global__ __launch_bounds__(512, 2) void main_kernel(
    const float* __restrict__ enc, const int* __restrict__ mask,
    const short* __restrict__ WeF, const float* __restrict__ dpb4,
    const float* __restrict__ Wa, const float* __restrict__ ba,
    float* __restrict__ out, float* __restrict__ ctx_ws, float* __restrict__ ml_ws)
{
    __shared__ float sc[TS];
    __shared__ float wgt[TS];
    __shared__ float dpbs[ENC];
    __shared__ float was[ENC];

    int blk   = blockIdx.x;
    int b     = blk >> 4;            // / NCHUNK
    int chunk = blk & 15;
    int s_base = chunk * TS;
    int t    = threadIdx.x;
    int w    = t >> 6, lane = t & 63;
    int quad = lane >> 4, l16 = lane & 15;

    // per-block small vectors -> LDS (before the only pre-K barrier)
    if (t < ENC) {
        dpbs[t] = dpb4[t] + dpb4[ENC + t] + dpb4[2 * ENC + t] + dpb4[3 * ENC + t]
                + 0.f;   // placeholder; real base added below
        // note: dpb4 is indexed per batch:
    }
    // (redo with batch offset; kept simple & correct:)
    if (t < ENC) {
        const float* dp = dpb4 + (size_t)b * 4 * ENC;
        dpbs[t] = dp[t] + dp[ENC + t] + dp[2 * ENC + t] + dp[3 * ENC + t];
        was[t]  = Wa[t];
    }
    __syncthreads();   // drains nothing heavy; A prefetches issued after

    const float* encB = enc + (size_t)b * SEQ * ENC;
    int row0 = s_base + w * 32 + l16;       // mt=0 row
    const float* aR0 = encB + (size_t)row0 * ENC + quad * 8;
    const float* aR1 = aR0 + 16 * ENC;      // mt=1 row

    floatx4 acc[2][16];
#pragma unroll
    for (int mt = 0; mt < 2; ++mt)
#pragma unroll
        for (int nt = 0; nt < 16; ++nt)
            acc[mt][nt] = (floatx4){0.f, 0.f, 0.f, 0.f};

    // 3-deep A prefetch pipeline (12 x floatx4 = 48 VGPRs)
    floatx4 p0[3], p1[3], p2[3], p3[3];
#pragma unroll
    for (int p = 0; p < 3; ++p) {
        p0[p] = *(const floatx4*)(aR0 + p * 32);
        p1[p] = *(const floatx4*)(aR0 + p * 32 + 4);
        p2[p] = *(const floatx4*)(aR1 + p * 32);
        p3[p] = *(const floatx4*)(aR1 + p * 32 + 4);
    }

#pragma unroll
    for (int kt = 0; kt < 8; ++kt) {
        const int s = kt % 3;
        short8 a0, a1;
#pragma unroll
        for (int j = 0; j < 4; ++j) {
            a0[j] = f2bf(p0[s][j]);  a0[j + 4] = f2bf(p1[s][j]);
            a1[j] = f2bf(p2[s][j]);  a1[j + 4] = f2bf(p3[s][j]);
        }
        if (kt < 5) {   // refill consumed slot with kt+3
            p0[s] = *(const floatx4*)(aR0 + (kt + 3) * 32);
            p1[s] = *(const floatx4*)(aR0 + (kt + 3) * 32 + 4);
            p2[s] = *(const floatx4*)(aR1 + (kt + 3) * 32);
            p3[s] = *(const floatx4*)(aR1 + (kt + 3) * 32 + 4);
        }
        const short* bp = WeF + (size_t)(kt * 16 * 64 + lane) * 8;
#pragma unroll
        for (int ng = 0; ng < 4; ++ng) {    // groups of 4 nt: batch the L1 loads
            short8 bf0 = *(const short8*)(bp + (ng * 4 + 0) * 512);
            short8 bf1 = *(const short8*)(bp + (ng * 4 + 1) * 512);
            short8 bf2 = *(const short8*)(bp + (ng * 4 + 2) * 512);
            short8 bf3 = *(const short8*)(bp + (ng * 4 + 3) * 512);
            acc[0][ng * 4 + 0] = __builtin_amdgcn_mfma_f32_16x16x32_bf16(a0, bf0, acc[0][ng * 4 + 0], 0, 0, 0);
            acc[1][ng * 4 + 0] = __builtin_amdgcn_mfma_f32_16x16x32_bf16(a1, bf0, acc[1][ng * 4 + 0], 0, 0, 0);
            acc[0][ng * 4 + 1] = __builtin_amdgcn_mfma_f32_16x16x32_bf16(a0, bf1, acc[0][ng * 4 + 1], 0, 0, 0);
            acc[1][ng * 4 + 1] = __builtin_amdgcn_mfma_f32_16x16x32_bf16(a1, bf1, acc[1][ng * 4 + 1], 0, 0, 0);
            acc[0][ng * 4 + 2] = __builtin_amdgcn_mfma_f32_16x16x32_bf16(a0, bf2, acc[0][ng * 4 + 2], 0, 0, 0);
            acc[1][ng * 4 + 2] = __builtin_amdgcn_mfma_f32_16x16x32_bf16(a1, bf2, acc[1][ng * 4 + 2], 0, 0, 0);
            acc[0][ng * 4 + 3] = __builtin_amdgcn_mfma_f32_16x16x32_bf16(a0, bf3, acc[0][ng * 4 + 3], 0, 0, 0);
            acc[1][ng * 4 + 3] = __builtin_amdgcn_mfma_f32_16x16x32_bf16(a1, bf3, acc[1][ng * 4 + 3], 0, 0, 0);
        }
    }

    // Epilogue: score_row = ba + sum_n Wa[n]*tanh(P[row][n] + dpb[n])
    float ba0 = ba[0];
    float part[2][4] = {{0.f,0.f,0.f,0.f},{0.f,0.f,0.f,0.f}};
#pragma unroll
    for (int nt = 0; nt < 16; ++nt) {
        int n = nt * 16 + l16;
        float wa  = was[n];
        float dpv = dpbs[n];
#pragma unroll
        for (int mt = 0; mt < 2; ++mt)
#pragma unroll
            for (int r = 0; r < 4; ++r)
                part[mt][r] = fmaf(wa, fast_tanh(acc[mt][nt][r] + dpv), part[mt][r]);
    }
#pragma unroll
    for (int mt = 0; mt < 2; ++mt) {
#pragma unroll
        for (int r = 0; r < 4; ++r) {
            float v = part[mt][r];
            v += __shfl_xor(v, 1);
            v += __shfl_xor(v, 2);
            v += __shfl_xor(v, 4);
            v += __shfl_xor(v, 8);
            part[mt][r] = v;
        }
        if (l16 == 0) {
            int idx0 = w * 32 + mt * 16 + quad * 4;
            int s0 = s_base + idx0;
            const int4 mv = *(const int4*)(mask + b * SEQ + s0);
            int mvals[4] = {mv.x, mv.y, mv.z, mv.w};
#pragma unroll
            for (int r = 0; r < 4; ++r) {
                float scv = part[mt][r] + ba0;
                if (mvals[r] == 0) scv = -1e10f;
                sc[idx0 + r] = scv;
                out[OUT_ATTN + (size_t)b * SEQ + s0 + r] = scv;   // raw; normalized by final
            }
        }
    }
    __syncthreads();

    // block softmax: every wave redundantly reduces the 256 scores
    float v0 = sc[lane], v1 = sc[lane + 64], v2 = sc[lane + 128], v3 = sc[lane + 192];
    float m = fmaxf(fmaxf(v0, v1), fmaxf(v2, v3));
    m = fmaxf(m, __shfl_xor(m, 1));
    m = fmaxf(m, __shfl_xor(m, 2));
    m = fmaxf(m, __shfl_xor(m, 4));
    m = fmaxf(m, __shfl_xor(m, 8));
    m = fmaxf(m, __shfl_xor(m, 16));
    m = fmaxf(m, __shfl_xor(m, 32));
    float e0 = __expf(v0 - m), e1 = __expf(v1 - m), e2 = __expf(v2 - m), e3 = __expf(v3 - m);
    float l = (e0 + e1) + (e2 + e3);
    l += __shfl_xor(l, 1);
    l += __shfl_xor(l, 2);
    l += __shfl_xor(l, 4);
    l += __shfl_xor(l, 8);
    l += __shfl_xor(l, 16);
    l += __shfl_xor(l, 32);
    if (t < TS) wgt[t] = __expf(sc[t] - m);
    __syncthreads();

    // unnormalized context partial over this chunk's 256 positions.
    // thread t: e-col = t&255, half h = t>>8 covers 128 positions. Tile is L2-hot.
    int ecol = t & 255, h = t >> 8;
    float c0 = 0.f, c1 = 0.f, c2 = 0.f, c3 = 0.f;
    const float* ep = encB + (size_t)(s_base + h * 128) * ENC + ecol;
    const float* wp = wgt + h * 128;
#pragma unroll 4
    for (int s2 = 0; s2 < 128; s2 += 4) {
        c0 = fmaf(wp[s2],     ep[(size_t)(s2)     * ENC], c0);
        c1 = fmaf(wp[s2 + 1], ep[(size_t)(s2 + 1) * ENC], c1);
        c2 = fmaf(wp[s2 + 2], ep[(size_t)(s2 + 2) * ENC], c2);
        c3 = fmaf(wp[s2 + 3], ep[(size_t)(s2 + 3) * ENC], c3);
    }
    float ctx = (c0 + c1) + (c2 + c3);

    int cidx = b * NCHUNK + chunk;
    ctx_ws[((size_t)cidx * 2 + h) * ENC + ecol] = ctx;
    if (t == 0) {
        ml_ws[cidx * 2]     = m;
        ml_ws[cidx * 2 + 1] = l;
    }
}

// Kernel 4: combine chunk partials per batch; finalize context and attn
__global__ void final_kernel(const float* __restrict__ ctx_ws,
                             const float* __restrict__ ml_ws,
                             float* __restrict__ out) {
    int b = blockIdx.x, t = threadIdx.x;
    float m = -3.4e38f;
    for (int c = 0; c < NCHUNK; ++c)
        m = fmaxf(m, ml_ws[(b * NCHUNK + c) * 2]);
    float L = 0.f;
    for (int c = 0; c < NCHUNK; ++c)
        L += ml_ws[(b * NCHUNK + c) * 2 + 1] * __expf(ml_ws[(b * NCHUNK + c) * 2] - m);
    float inv = 1.0f / L;

    float cx = 0.f;
    for (int c = 0; c < NCHUNK; ++c) {
        float sc_c = __expf(ml_ws[(b * NCHUNK + c) * 2] - m);
        size_t base = ((size_t)(b * NCHUNK + c) * 2) * ENC + t;
        cx += sc_c * (ctx_ws[base] + ctx_ws[base + ENC]);
    }
    out[b * ENC + t] = cx * inv;

    for (int s = t; s < SEQ; s += 256) {
        float raw = out[OUT_ATTN + (size_t)b * SEQ + s];
        out[OUT_ATTN + (size_t)b * SEQ + s] = __expf(raw - m) * inv;
    }
}

extern "C" void kernel_launch(void* const* d_in, const int* in_sizes, int n_in,
                              void* d_out, int out_size, void* d_ws, size_t ws_size,
                              hipStream_t stream) {
    const float* dh   = (const float*)d_in[0];
    const float* enc  = (const float*)d_in[1];
    const int*   mask = (const int*)d_in[2];
    const float* Wd   = (const float*)d_in[3];
    const float* bd   = (const float*)d_in[4];
    const float* We   = (const float*)d_in[5];
    const float* be   = (const float*)d_in[6];
    const float* Wa   = (const float*)d_in[7];
    const float* ba   = (const float*)d_in[8];
    float* out = (float*)d_out;

    // ws layout (floats): ctx_ws[64*16*2*256] | ml_ws[64*16*2] | dpb4[64*4*256] | WeF (bf16, 64K shorts)
    float* w      = (float*)d_ws;
    float* ctx_ws = w;
    float* ml_ws  = w + BATCH * NCHUNK * 2 * ENC;
    float* dpb4   = ml_ws + BATCH * NCHUNK * 2;
    short* WeF    = (short*)(dpb4 + BATCH * 4 * ENC);

    hipLaunchKernelGGL(dp_kernel,   dim3(BATCH * 4),         dim3(256), 0, stream, dh, Wd, bd, be, dpb4);
    hipLaunchKernelGGL(pack_kernel, dim3(32),                dim3(256), 0, stream, We, WeF);
    hipLaunchKernelGGL(main_kernel, dim3(BATCH * NCHUNK),    dim3(512), 0, stream,
                       enc, mask, WeF, dpb4, Wa, ba, out, ctx_ws, ml_ws);
    hipLaunchKernelGGL(final_kernel, dim3(BATCH),            dim3(256), 0, stream, ctx_ws, ml_ws, out);
}

// Round 4
// 415.713 us; speedup vs baseline: 1.2891x; 1.2891x over previous
//
#include <hip/hip_runtime.h>

#define BATCH 64
#define SEQ   4096
#define DECD  512
#define ENC   256
#define TS    128                // rows per block (8 waves x 16 rows)
#define NCHUNK (SEQ / TS)        // 32 chunks per batch
#define OUT_ATTN (BATCH * ENC)   // offset of attn region in d_out

typedef short  short8  __attribute__((ext_vector_type(8)));
typedef float  floatx4 __attribute__((ext_vector_type(4)));

__device__ __forceinline__ short f2bf(float f) {
    union { float f; unsigned u; } v; v.f = f;
    unsigned u = v.u;
    u += 0x7FFFu + ((u >> 16) & 1u);
    return (short)(u >> 16);
}

__device__ __forceinline__ float fast_tanh(float x) {
    x = fminf(fmaxf(x, -9.0f), 9.0f);
    float e2 = __expf(2.0f * x);
    float r  = __builtin_amdgcn_rcpf(e2 + 1.0f);
    return fmaf(-2.0f, r, 1.0f);
}

// async global->LDS, 16B per lane. LDS dest = wave-uniform base + lane*16.
__device__ __forceinline__ void gload_lds16(const short* g, short* l) {
    __builtin_amdgcn_global_load_lds(
        (const __attribute__((address_space(1))) unsigned int*)g,
        (__attribute__((address_space(3))) unsigned int*)l,
        16, 0, 0);
}

// Kernel 1 (split-K x4): dpb4[(b*4+j)][e] = partial sum (+ bd+be on j==0)
__global__ void dp_kernel(const float* __restrict__ dh,
                          const float* __restrict__ Wd,
                          const float* __restrict__ bd,
                          const float* __restrict__ be,
                          float* __restrict__ dpb4) {
    __shared__ float dhs[128];
    int blk = blockIdx.x, b = blk >> 2, j = blk & 3;
    int t = threadIdx.x;
    if (t < 128) dhs[t] = dh[b * DECD + j * 128 + t];
    __syncthreads();
    const float* wp = Wd + (size_t)(j * 128) * ENC + t;
    float a0 = 0.f, a1 = 0.f, a2 = 0.f, a3 = 0.f;
#pragma unroll 4
    for (int d = 0; d < 128; d += 4) {
        a0 = fmaf(dhs[d],     wp[(size_t)(d)     * ENC], a0);
        a1 = fmaf(dhs[d + 1], wp[(size_t)(d + 1) * ENC], a1);
        a2 = fmaf(dhs[d + 2], wp[(size_t)(d + 2) * ENC], a2);
        a3 = fmaf(dhs[d + 3], wp[(size_t)(d + 3) * ENC], a3);
    }
    float r = (a0 + a1) + (a2 + a3);
    if (j == 0) r += bd[t] + be[t];
    dpb4[(size_t)(b * 4 + j) * ENC + t] = r;
}

// Kernel 2: pack We into bf16 MFMA B-fragment layout; each kt slice = contiguous 16KB.
__global__ void pack_kernel(const float* __restrict__ We, short* __restrict__ WeF) {
    int gid  = blockIdx.x * 256 + threadIdx.x;   // 0..8191
    int lane = gid & 63;
    int nt   = (gid >> 6) & 15;
    int kt   = gid >> 10;
    int quad = lane >> 4, l16 = lane & 15;
    int n = nt * 16 + l16;
    short8 v;
#pragma unroll
    for (int j = 0; j < 8; ++j) {
        int k = kt * 32 + quad * 8 + j;
        v[j] = f2bf(We[k * ENC + n]);
    }
    *(short8*)(WeF + gid * 8) = v;
}

// Kernel 3 (main): block = (b, chunk of 128 rows); 8 waves, 1 M-tile/wave (acc=64).
// B: half of WeF (4 kt slices, 64KB) staged per phase -> 4 barrier-free kt per stage.
__global__ __launch_bounds__(512, 4) void main_kernel(
    const float* __restrict__ enc, const int* __restrict__ mask,
    const short* __restrict__ WeF, const float* __restrict__ dpb4,
    const float* __restrict__ Wa, const float* __restrict__ ba,
    float* __restrict__ out, float* __restrict__ ctx_ws, float* __restrict__ ml_ws)
{
    __shared__ short Bs[32768];      // 64 KB: B phase buffer; overlaid by epilogue arrays
    float* F    = (float*)Bs;        // overlay (valid after K-loop):
    float* scF  = F;                 // [0,128)   scores
    float* wgtF = F + 128;           // [128,256) weights
    float* dpbF = F + 256;           // [256,512) dpb
    float* waF  = F + 512;           // [512,768) Wa

    int blk   = blockIdx.x;
    int b     = blk >> 5;            // / NCHUNK
    int chunk = blk & 31;
    int s_base = chunk * TS;
    int t    = threadIdx.x;
    int w    = t >> 6, lane = t & 63;
    int quad = lane >> 4, l16 = lane & 15;

    const float* encB = enc + (size_t)b * SEQ * ENC;
    int row = s_base + w * 16 + l16;
    const float* aRow = encB + (size_t)row * ENC + quad * 8;

    floatx4 acc[16];
#pragma unroll
    for (int nt = 0; nt < 16; ++nt) acc[nt] = (floatx4){0.f, 0.f, 0.f, 0.f};

    // 3-deep A prefetch pipeline (6 x floatx4 = 24 VGPRs)
    floatx4 p0[3], p1[3];
#pragma unroll
    for (int p = 0; p < 3; ++p) {
        p0[p] = *(const floatx4*)(aRow + p * 32);
        p1[p] = *(const floatx4*)(aRow + p * 32 + 4);
    }

    // stage phase 0: WeF slices 0..3 (64KB). 8 rounds x 512 threads x 16B.
#pragma unroll
    for (int j = 0; j < 8; ++j) {
        int c = j * 8 + w;           // chunk 0..63, 512 shorts each
        gload_lds16(WeF + c * 512 + lane * 8, Bs + c * 512 + lane * 8);
    }
    __syncthreads();

#pragma unroll
    for (int kkt = 0; kkt < 4; ++kkt) {
        const int s = kkt % 3;
        short8 a;
#pragma unroll
        for (int j = 0; j < 4; ++j) { a[j] = f2bf(p0[s][j]); a[j + 4] = f2bf(p1[s][j]); }
        if (kkt < 5) {
            p0[s] = *(const floatx4*)(aRow + (kkt + 3) * 32);
            p1[s] = *(const floatx4*)(aRow + (kkt + 3) * 32 + 4);
        }
        const short* bp = Bs + kkt * 8192 + lane * 8;
#pragma unroll
        for (int ng = 0; ng < 4; ++ng) {
            short8 bf0 = *(const short8*)(bp + (ng * 4 + 0) * 512);
            short8 bf1 = *(const short8*)(bp + (ng * 4 + 1) * 512);
            short8 bf2 = *(const short8*)(bp + (ng * 4 + 2) * 512);
            short8 bf3 = *(const short8*)(bp + (ng * 4 + 3) * 512);
            acc[ng * 4 + 0] = __builtin_amdgcn_mfma_f32_16x16x32_bf16(a, bf0, acc[ng * 4 + 0], 0, 0, 0);
            acc[ng * 4 + 1] = __builtin_amdgcn_mfma_f32_16x16x32_bf16(a, bf1, acc[ng * 4 + 1], 0, 0, 0);
            acc[ng * 4 + 2] = __builtin_amdgcn_mfma_f32_16x16x32_bf16(a, bf2, acc[ng * 4 + 2], 0, 0, 0);
            acc[ng * 4 + 3] = __builtin_amdgcn_mfma_f32_16x16x32_bf16(a, bf3, acc[ng * 4 + 3], 0, 0, 0);
        }
    }

    __syncthreads();                  // all waves done reading phase-0 B
    // stage phase 1: WeF slices 4..7 into the same buffer
#pragma unroll
    for (int j = 0; j < 8; ++j) {
        int c = j * 8 + w;
        gload_lds16(WeF + 32768 + c * 512 + lane * 8, Bs + c * 512 + lane * 8);
    }
    __syncthreads();

#pragma unroll
    for (int kkt = 4; kkt < 8; ++kkt) {
        const int s = kkt % 3;
        short8 a;
#pragma unroll
        for (int j = 0; j < 4; ++j) { a[j] = f2bf(p0[s][j]); a[j + 4] = f2bf(p1[s][j]); }
        if (kkt < 5) {
            p0[s] = *(const floatx4*)(aRow + (kkt + 3) * 32);
            p1[s] = *(const floatx4*)(aRow + (kkt + 3) * 32 + 4);
        }
        const short* bp = Bs + (kkt - 4) * 8192 + lane * 8;
#pragma unroll
        for (int ng = 0; ng < 4; ++ng) {
            short8 bf0 = *(const short8*)(bp + (ng * 4 + 0) * 512);
            short8 bf1 = *(const short8*)(bp + (ng * 4 + 1) * 512);
            short8 bf2 = *(const short8*)(bp + (ng * 4 + 2) * 512);
            short8 bf3 = *(const short8*)(bp + (ng * 4 + 3) * 512);
            acc[ng * 4 + 0] = __builtin_amdgcn_mfma_f32_16x16x32_bf16(a, bf0, acc[ng * 4 + 0], 0, 0, 0);
            acc[ng * 4 + 1] = __builtin_amdgcn_mfma_f32_16x16x32_bf16(a, bf1, acc[ng * 4 + 1], 0, 0, 0);
            acc[ng * 4 + 2] = __builtin_amdgcn_mfma_f32_16x16x32_bf16(a, bf2, acc[ng * 4 + 2], 0, 0, 0);
            acc[ng * 4 + 3] = __builtin_amdgcn_mfma_f32_16x16x32_bf16(a, bf3, acc[ng * 4 + 3], 0, 0, 0);
        }
    }

    __syncthreads();                  // B dead; overlay epilogue arrays
    if (t < 256) {
        const float* dp = dpb4 + (size_t)b * 4 * ENC;
        dpbF[t] = dp[t] + dp[ENC + t] + dp[2 * ENC + t] + dp[3 * ENC + t];
    } else {
        waF[t - 256] = Wa[t - 256];
    }
    __syncthreads();

    // score_row = ba + sum_n Wa[n]*tanh(P[row][n] + dpb[n])
    float ba0 = ba[0];
    float part[4] = {0.f, 0.f, 0.f, 0.f};
#pragma unroll
    for (int nt = 0; nt < 16; ++nt) {
        int n = nt * 16 + l16;
        float wa  = waF[n];
        float dpv = dpbF[n];
#pragma unroll
        for (int r = 0; r < 4; ++r)
            part[r] = fmaf(wa, fast_tanh(acc[nt][r] + dpv), part[r]);
    }
#pragma unroll
    for (int r = 0; r < 4; ++r) {
        float v = part[r];
        v += __shfl_xor(v, 1);
        v += __shfl_xor(v, 2);
        v += __shfl_xor(v, 4);
        v += __shfl_xor(v, 8);
        part[r] = v;
    }
    if (l16 == 0) {
        int idx0 = w * 16 + quad * 4;
        int s0 = s_base + idx0;
        const int4 mv = *(const int4*)(mask + b * SEQ + s0);
        int mvals[4] = {mv.x, mv.y, mv.z, mv.w};
#pragma unroll
        for (int r = 0; r < 4; ++r) {
            float scv = part[r] + ba0;
            if (mvals[r] == 0) scv = -1e10f;
            scF[idx0 + r] = scv;
            out[OUT_ATTN + (size_t)b * SEQ + s0 + r] = scv;   // raw; final normalizes
        }
    }
    __syncthreads();

    // block softmax over 128 scores (each wave redundantly, via shuffles)
    float v0 = scF[lane], v1 = scF[lane + 64];
    float m = fmaxf(v0, v1);
    m = fmaxf(m, __shfl_xor(m, 1));
    m = fmaxf(m, __shfl_xor(m, 2));
    m = fmaxf(m, __shfl_xor(m, 4));
    m = fmaxf(m, __shfl_xor(m, 8));
    m = fmaxf(m, __shfl_xor(m, 16));
    m = fmaxf(m, __shfl_xor(m, 32));
    float e0 = __expf(v0 - m), e1 = __expf(v1 - m);
    float l = e0 + e1;
    l += __shfl_xor(l, 1);
    l += __shfl_xor(l, 2);
    l += __shfl_xor(l, 4);
    l += __shfl_xor(l, 8);
    l += __shfl_xor(l, 16);
    l += __shfl_xor(l, 32);
    if (t < TS) wgtF[t] = __expf(scF[t] - m);
    __syncthreads();

    // unnormalized context partial: thread t -> ecol = t&255, seg = t>>8 (64 rows each)
    int ecol = t & 255, seg = t >> 8;
    float c0 = 0.f, c1 = 0.f, c2 = 0.f, c3 = 0.f;
    const float* ep = encB + (size_t)(s_base + seg * 64) * ENC + ecol;
    const float* wp = wgtF + seg * 64;
#pragma unroll 4
    for (int s2 = 0; s2 < 64; s2 += 4) {
        c0 = fmaf(wp[s2],     ep[(size_t)(s2)     * ENC], c0);
        c1 = fmaf(wp[s2 + 1], ep[(size_t)(s2 + 1) * ENC], c1);
        c2 = fmaf(wp[s2 + 2], ep[(size_t)(s2 + 2) * ENC], c2);
        c3 = fmaf(wp[s2 + 3], ep[(size_t)(s2 + 3) * ENC], c3);
    }
    float ctx = (c0 + c1) + (c2 + c3);

    int cidx = b * NCHUNK + chunk;
    ctx_ws[((size_t)cidx * 2 + seg) * ENC + ecol] = ctx;
    if (t == 0) {
        ml_ws[cidx * 2]     = m;
        ml_ws[cidx * 2 + 1] = l;
    }
}

// Kernel 4: combine chunk partials per batch; finalize context and attn
__global__ void final_kernel(const float* __restrict__ ctx_ws,
                             const float* __restrict__ ml_ws,
                             float* __restrict__ out) {
    int b = blockIdx.x, t = threadIdx.x;
    float m = -3.4e38f;
    for (int c = 0; c < NCHUNK; ++c)
        m = fmaxf(m, ml_ws[(b * NCHUNK + c) * 2]);
    float L = 0.f;
    for (int c = 0; c < NCHUNK; ++c)
        L += ml_ws[(b * NCHUNK + c) * 2 + 1] * __expf(ml_ws[(b * NCHUNK + c) * 2] - m);
    float inv = 1.0f / L;

    float cx = 0.f;
    for (int c = 0; c < NCHUNK; ++c) {
        float sc_c = __expf(ml_ws[(b * NCHUNK + c) * 2] - m);
        size_t base = ((size_t)(b * NCHUNK + c) * 2) * ENC + t;
        cx += sc_c * (ctx_ws[base] + ctx_ws[base + ENC]);
    }
    out[b * ENC + t] = cx * inv;

    for (int s = t; s < SEQ; s += 256) {
        float raw = out[OUT_ATTN + (size_t)b * SEQ + s];
        out[OUT_ATTN + (size_t)b * SEQ + s] = __expf(raw - m) * inv;
    }
}

extern "C" void kernel_launch(void* const* d_in, const int* in_sizes, int n_in,
                              void* d_out, int out_size, void* d_ws, size_t ws_size,
                              hipStream_t stream) {
    const float* dh   = (const float*)d_in[0];
    const float* enc  = (const float*)d_in[1];
    const int*   mask = (const int*)d_in[2];
    const float* Wd   = (const float*)d_in[3];
    const float* bd   = (const float*)d_in[4];
    const float* We   = (const float*)d_in[5];
    const float* be   = (const float*)d_in[6];
    const float* Wa   = (const float*)d_in[7];
    const float* ba   = (const float*)d_in[8];
    float* out = (float*)d_out;

    // ws (floats): ctx_ws[64*32*2*256] | ml_ws[64*32*2] | dpb4[64*4*256] | WeF (bf16, 64K shorts)
    float* w      = (float*)d_ws;
    float* ctx_ws = w;
    float* ml_ws  = w + BATCH * NCHUNK * 2 * ENC;
    float* dpb4   = ml_ws + BATCH * NCHUNK * 2;
    short* WeF    = (short*)(dpb4 + BATCH * 4 * ENC);

    hipLaunchKernelGGL(dp_kernel,   dim3(BATCH * 4),       dim3(256), 0, stream, dh, Wd, bd, be, dpb4);
    hipLaunchKernelGGL(pack_kernel, dim3(32),              dim3(256), 0, stream, We, WeF);
    hipLaunchKernelGGL(main_kernel, dim3(BATCH * NCHUNK),  dim3(512), 0, stream,
                       enc, mask, WeF, dpb4, Wa, ba, out, ctx_ws, ml_ws);
    hipLaunchKernelGGL(final_kernel, dim3(BATCH),          dim3(256), 0, stream, ctx_ws, ml_ws, out);
}